// Round 3
// baseline (801.686 us; speedup 1.0000x reference)
//
#include <hip/hip_runtime.h>

typedef unsigned int u32;
typedef unsigned short u16;

__device__ __forceinline__ float bf2f(u16 u){ return __uint_as_float(((u32)u) << 16); }
__device__ __forceinline__ u16 f2bf(float f){
  u32 x = __float_as_uint(f);
  return (u16)((x + 0x7fffu + ((x >> 16) & 1u)) >> 16);  // RNE
}

// ---------- build concatenated weight Wcat[128][640], cols: [q | skip | k | v | gcn] ----------
__global__ void k_prep(const float* wq, const float* bq, const float* wsk, const float* bsk,
                       const float* wk, const float* bk, const float* wv, const float* bv,
                       const float* wg, float* Wcat, float* bcat){
  int idx = blockIdx.x * 256 + threadIdx.x;     // 0 .. 128*640-1
  int col = idx % 640, k = idx / 640;
  int blk = col >> 7, c = col & 127;
  const float* w; const float* b;
  switch (blk){
    case 0:  w = wq;  b = bq;  break;
    case 1:  w = wsk; b = bsk; break;
    case 2:  w = wk;  b = bk;  break;
    case 3:  w = wv;  b = bv;  break;
    default: w = wg;  b = nullptr; break;       // gcn bias added AFTER aggregation
  }
  Wcat[k * 640 + col] = w[k * 128 + c];
  if (k == 0) bcat[col] = b ? b[c] : 0.0f;
}

// ---------- in-degree histogram (edge_index is int32: src=ei[e], dst=ei[E+e]) ----------
__global__ void k_hist(const int* __restrict__ ei, int E, int* __restrict__ deg){
  int e = blockIdx.x * 256 + threadIdx.x;
  if (e >= E) return;
  atomicAdd(&deg[ei[E + e]], 1);
}

// ---------- exclusive scan of deg -> rowptr (3 small kernels) ----------
__global__ void k_scan_a(const int* __restrict__ deg, int N, int* __restrict__ bsum){
  __shared__ int sh[256];
  int b = blockIdx.x, t = threadIdx.x;
  int base = b * 1024 + t * 4, s = 0;
  #pragma unroll
  for (int j = 0; j < 4; j++){ int i = base + j; if (i < N) s += deg[i]; }
  sh[t] = s; __syncthreads();
  for (int off = 128; off > 0; off >>= 1){ if (t < off) sh[t] += sh[t + off]; __syncthreads(); }
  if (t == 0) bsum[b] = sh[0];
}
__global__ void k_scan_b(const int* __restrict__ bsum, int NB, int* __restrict__ boff){
  __shared__ int sh[1024];
  int t = threadIdx.x;
  int self = (t < NB) ? bsum[t] : 0;
  sh[t] = self; __syncthreads();
  for (int off = 1; off < 1024; off <<= 1){
    int v = sh[t]; int add = (t >= off) ? sh[t - off] : 0;
    __syncthreads(); sh[t] = v + add; __syncthreads();
  }
  if (t < NB) boff[t] = sh[t] - self;   // exclusive
}
__global__ void k_scan_c(const int* __restrict__ deg, int N, int E,
                         const int* __restrict__ boff, int* __restrict__ rowptr){
  __shared__ int sh[256];
  int b = blockIdx.x, t = threadIdx.x;
  int base = b * 1024 + t * 4;
  int d[4]; int ts = 0;
  #pragma unroll
  for (int j = 0; j < 4; j++){ int i = base + j; d[j] = (i < N) ? deg[i] : 0; ts += d[j]; }
  sh[t] = ts; __syncthreads();
  for (int off = 1; off < 256; off <<= 1){
    int v = sh[t]; int add = (t >= off) ? sh[t - off] : 0;
    __syncthreads(); sh[t] = v + add; __syncthreads();
  }
  int excl = sh[t] - ts + boff[b];
  #pragma unroll
  for (int j = 0; j < 4; j++){ int i = base + j; if (i < N) rowptr[i] = excl; excl += d[j]; }
  if (b == 0 && t == 0) rowptr[N] = E;
}

__global__ void k_dinv(const int* __restrict__ deg, int N, float* __restrict__ dinv){
  int i = blockIdx.x * 256 + threadIdx.x;
  if (i < N) dinv[i] = deg[i] > 0 ? rsqrtf((float)deg[i]) : 0.0f;
}

__global__ void k_csr(const int* __restrict__ ei, int E,
                      const int* __restrict__ rowptr, int* __restrict__ fill, int* __restrict__ csr){
  int e = blockIdx.x * 256 + threadIdx.x;
  if (e >= E) return;
  int s = ei[e];
  int d = ei[E + e];
  int pos = rowptr[d] + atomicAdd(&fill[d], 1);
  csr[pos] = s;
}

// ---------- GEMM1: [q | xr | k,v,h] (all bf16) = x @ Wcat + bcat ----------
__global__ __launch_bounds__(256) void k_gemm1(const float* __restrict__ x, const float* __restrict__ Wcat,
    const float* __restrict__ bcat, u16* __restrict__ qB, u16* __restrict__ xrB,
    u16* __restrict__ kvhB, int N){
  __shared__ float As[64][68];   // [row][k-chunk]
  __shared__ float Bs[64][68];   // [k-chunk][col]
  int t = threadIdx.x, tx = t & 15, ty = t >> 4;
  int row0 = blockIdx.x * 64, col0 = blockIdx.y * 64;
  float acc[4][4] = {};
  for (int kc = 0; kc < 128; kc += 64){
    #pragma unroll
    for (int i = 0; i < 4; i++){
      int fid = t + 256 * i; int r = fid >> 4, k4 = (fid & 15) << 2;
      int row = row0 + r;
      float4 v = make_float4(0, 0, 0, 0);
      if (row < N) v = *(const float4*)(x + (size_t)row * 128 + kc + k4);
      *(float4*)&As[r][k4] = v;
    }
    #pragma unroll
    for (int i = 0; i < 4; i++){
      int fid = t + 256 * i; int k = fid >> 4, c4 = (fid & 15) << 2;
      *(float4*)&Bs[k][c4] = *(const float4*)(Wcat + (size_t)(kc + k) * 640 + col0 + c4);
    }
    __syncthreads();
    #pragma unroll 8
    for (int kk = 0; kk < 64; kk++){
      float b0 = Bs[kk][tx*4+0], b1 = Bs[kk][tx*4+1], b2 = Bs[kk][tx*4+2], b3 = Bs[kk][tx*4+3];
      #pragma unroll
      for (int i = 0; i < 4; i++){
        float a = As[ty*4+i][kk];
        acc[i][0] += a*b0; acc[i][1] += a*b1; acc[i][2] += a*b2; acc[i][3] += a*b3;
      }
    }
    __syncthreads();
  }
  float4 bc = *(const float4*)(bcat + col0 + tx * 4);
  int colg = col0 + tx * 4;
  #pragma unroll
  for (int i = 0; i < 4; i++){
    int row = row0 + ty * 4 + i;
    if (row >= N) break;
    ushort4 s;
    s.x = f2bf(acc[i][0] + bc.x);
    s.y = f2bf(acc[i][1] + bc.y);
    s.z = f2bf(acc[i][2] + bc.z);
    s.w = f2bf(acc[i][3] + bc.w);
    u16* dst;
    if (colg < 128)      dst = qB   + (size_t)row * 128 + colg;
    else if (colg < 256) dst = xrB  + (size_t)row * 128 + (colg - 128);
    else                 dst = kvhB + (size_t)row * 384 + (colg - 256);
    *(ushort4*)dst = s;
  }
}

// ---------- edge pass: per-dst attention + GCN aggregate + beta gate + LN1, one wave per node ----------
__global__ __launch_bounds__(256) void k_edge(const u16* __restrict__ qB, const u16* __restrict__ xrB,
    const u16* __restrict__ kvhB,
    const int* __restrict__ csr, const int* __restrict__ rowptr, const float* __restrict__ dinv,
    const float* __restrict__ bgcn, const float* __restrict__ wbeta,
    const float* __restrict__ lng, const float* __restrict__ lnb,
    const float* __restrict__ lwp, const float* __restrict__ gwp,
    float* __restrict__ xn, int N){
  int lane = threadIdx.x & 63;
  int n = blockIdx.x * 4 + (threadIdx.x >> 6);
  if (n >= N) return;
  int ro = rowptr[n], re = rowptr[n + 1];
  u32 qu = *(const u32*)(qB + (size_t)n * 128 + 2 * lane);
  float q0 = bf2f((u16)(qu & 0xffff)), q1 = bf2f((u16)(qu >> 16));
  float av0 = 0, av1 = 0, ah0 = 0, ah1 = 0, den = 0;
  int sNext = (ro < re) ? csr[ro] : 0;
  for (int e = ro; e < re; e++){
    int s = sNext;
    if (e + 1 < re) sNext = csr[e + 1];
    const u16* fb = kvhB + (size_t)s * 384;
    u32 ku = *(const u32*)(fb + 2 * lane);
    u32 vu = *(const u32*)(fb + 128 + 2 * lane);
    u32 hu = *(const u32*)(fb + 256 + 2 * lane);
    float dv = dinv[s];
    float k0 = bf2f((u16)(ku & 0xffff)), k1 = bf2f((u16)(ku >> 16));
    float part = q0 * k0 + q1 * k1;                 // head = lane/16; reduce within 16-lane group
    part += __shfl_xor(part, 1);
    part += __shfl_xor(part, 2);
    part += __shfl_xor(part, 4);
    part += __shfl_xor(part, 8);
    float p = __expf(part * 0.17677669529663687f);  // 1/sqrt(32); scores ~N(0,1), no max-shift needed
    float v0 = bf2f((u16)(vu & 0xffff)), v1 = bf2f((u16)(vu >> 16));
    float h0 = bf2f((u16)(hu & 0xffff)), h1 = bf2f((u16)(hu >> 16));
    av0 += p * v0; av1 += p * v1;
    ah0 += dv * h0; ah1 += dv * h1;
    den += p;
  }
  float at0 = den > 0 ? av0 / den : 0.0f;
  float at1 = den > 0 ? av1 / den : 0.0f;
  u32 xru = *(const u32*)(xrB + (size_t)n * 128 + 2 * lane);
  float xr0 = bf2f((u16)(xru & 0xffff)), xr1 = bf2f((u16)(xru >> 16));
  // beta = sigmoid([attn | xr | attn-xr] . w_beta)  -- full-wave reduce
  float z = at0 * wbeta[2*lane] + at1 * wbeta[2*lane+1]
          + xr0 * wbeta[128 + 2*lane] + xr1 * wbeta[129 + 2*lane]
          + (at0 - xr0) * wbeta[256 + 2*lane] + (at1 - xr1) * wbeta[257 + 2*lane];
  z += __shfl_xor(z, 1); z += __shfl_xor(z, 2); z += __shfl_xor(z, 4);
  z += __shfl_xor(z, 8); z += __shfl_xor(z, 16); z += __shfl_xor(z, 32);
  float beta = 1.0f / (1.0f + __expf(-z));
  float dn = dinv[n];
  float l0 = dn * ah0 + bgcn[2*lane], l1 = dn * ah1 + bgcn[2*lane+1];
  float g0 = beta * xr0 + (1.0f - beta) * at0;
  float g1v = beta * xr1 + (1.0f - beta) * at1;
  float lw = lwp[0], gw = gwp[0];
  float t0 = 2.0f * (lw * l0 + gw * g0);
  float t1 = 2.0f * (lw * l1 + gw * g1v);
  // LN1 over 128 elems (full-wave reduce of sum & sumsq)
  float s = t0 + t1, sq = t0 * t0 + t1 * t1;
  s += __shfl_xor(s, 1);  sq += __shfl_xor(sq, 1);
  s += __shfl_xor(s, 2);  sq += __shfl_xor(sq, 2);
  s += __shfl_xor(s, 4);  sq += __shfl_xor(sq, 4);
  s += __shfl_xor(s, 8);  sq += __shfl_xor(sq, 8);
  s += __shfl_xor(s, 16); sq += __shfl_xor(sq, 16);
  s += __shfl_xor(s, 32); sq += __shfl_xor(sq, 32);
  float mu = s * (1.0f / 128.0f);
  float var = sq * (1.0f / 128.0f) - mu * mu;
  float inv = rsqrtf(var + 1e-5f);
  float o0 = (t0 - mu) * inv * lng[2*lane] + lnb[2*lane];
  float o1 = (t1 - mu) * inv * lng[2*lane+1] + lnb[2*lane+1];
  *(float2*)(xn + (size_t)n * 128 + 2 * lane) = make_float2(o0, o1);
}

// ---------- FFN1: hid(bf16) = relu(xn @ w1 + b1), [N,128]->[N,256] ----------
__global__ __launch_bounds__(256) void k_ffn1(const float* __restrict__ xn, const float* __restrict__ w1,
    const float* __restrict__ b1, u16* __restrict__ hid, int N){
  __shared__ float As[64][68];
  __shared__ float Bs[64][68];
  int t = threadIdx.x, tx = t & 15, ty = t >> 4;
  int row0 = blockIdx.x * 64, col0 = blockIdx.y * 64;
  float acc[4][4] = {};
  for (int kc = 0; kc < 128; kc += 64){
    #pragma unroll
    for (int i = 0; i < 4; i++){
      int fid = t + 256 * i; int r = fid >> 4, k4 = (fid & 15) << 2;
      int row = row0 + r;
      float4 v = make_float4(0, 0, 0, 0);
      if (row < N) v = *(const float4*)(xn + (size_t)row * 128 + kc + k4);
      *(float4*)&As[r][k4] = v;
    }
    #pragma unroll
    for (int i = 0; i < 4; i++){
      int fid = t + 256 * i; int k = fid >> 4, c4 = (fid & 15) << 2;
      *(float4*)&Bs[k][c4] = *(const float4*)(w1 + (size_t)(kc + k) * 256 + col0 + c4);
    }
    __syncthreads();
    #pragma unroll 8
    for (int kk = 0; kk < 64; kk++){
      float b0 = Bs[kk][tx*4+0], b1v = Bs[kk][tx*4+1], b2 = Bs[kk][tx*4+2], b3 = Bs[kk][tx*4+3];
      #pragma unroll
      for (int i = 0; i < 4; i++){
        float a = As[ty*4+i][kk];
        acc[i][0] += a*b0; acc[i][1] += a*b1v; acc[i][2] += a*b2; acc[i][3] += a*b3;
      }
    }
    __syncthreads();
  }
  float4 bb = *(const float4*)(b1 + col0 + tx * 4);
  #pragma unroll
  for (int i = 0; i < 4; i++){
    int row = row0 + ty * 4 + i;
    if (row >= N) break;
    ushort4 o;
    o.x = f2bf(fmaxf(acc[i][0] + bb.x, 0.0f));
    o.y = f2bf(fmaxf(acc[i][1] + bb.y, 0.0f));
    o.z = f2bf(fmaxf(acc[i][2] + bb.z, 0.0f));
    o.w = f2bf(fmaxf(acc[i][3] + bb.w, 0.0f));
    *(ushort4*)(hid + (size_t)row * 256 + col0 + tx * 4) = o;
  }
}

// ---------- FFN2 + residual + LN2 -> out (in place over xn). 512 thr, tile 64x128 ----------
__global__ __launch_bounds__(512) void k_ffn2(const u16* __restrict__ hid, const float* __restrict__ w2,
    const float* __restrict__ b2, const float* __restrict__ xn,
    const float* __restrict__ g2, const float* __restrict__ bt2,
    float* __restrict__ out, int N){
  __shared__ float As[64][68];
  __shared__ float Bs[64][132];
  int t = threadIdx.x, tx = t & 31, ty = t >> 5;
  int row0 = blockIdx.x * 64;
  float acc[4][4] = {};
  for (int kc = 0; kc < 256; kc += 64){
    #pragma unroll
    for (int i = 0; i < 2; i++){
      int fid = t + 512 * i; int r = fid >> 4, k4 = (fid & 15) << 2;
      int row = row0 + r;
      ushort4 hv = make_ushort4(0, 0, 0, 0);
      if (row < N) hv = *(const ushort4*)(hid + (size_t)row * 256 + kc + k4);
      As[r][k4+0] = bf2f(hv.x);
      As[r][k4+1] = bf2f(hv.y);
      As[r][k4+2] = bf2f(hv.z);
      As[r][k4+3] = bf2f(hv.w);
    }
    #pragma unroll
    for (int i = 0; i < 4; i++){
      int fid = t + 512 * i; int k = fid >> 5, c4 = (fid & 31) << 2;
      *(float4*)&Bs[k][c4] = *(const float4*)(w2 + (size_t)(kc + k) * 128 + c4);
    }
    __syncthreads();
    #pragma unroll 8
    for (int kk = 0; kk < 64; kk++){
      float b0 = Bs[kk][tx*4+0], b1v = Bs[kk][tx*4+1], b2v = Bs[kk][tx*4+2], b3 = Bs[kk][tx*4+3];
      #pragma unroll
      for (int i = 0; i < 4; i++){
        float a = As[ty*4+i][kk];
        acc[i][0] += a*b0; acc[i][1] += a*b1v; acc[i][2] += a*b2v; acc[i][3] += a*b3;
      }
    }
    __syncthreads();
  }
  float4 bb  = *(const float4*)(b2 + tx * 4);
  float4 gg  = *(const float4*)(g2 + tx * 4);
  float4 b2t = *(const float4*)(bt2 + tx * 4);
  #pragma unroll
  for (int i = 0; i < 4; i++){
    int row = row0 + ty * 4 + i;
    int rc = row < N ? row : N - 1;
    float4 xv = *(const float4*)(xn + (size_t)rc * 128 + tx * 4);
    float z0 = acc[i][0] + bb.x + xv.x;
    float z1 = acc[i][1] + bb.y + xv.y;
    float z2 = acc[i][2] + bb.z + xv.z;
    float z3 = acc[i][3] + bb.w + xv.w;
    float s = z0 + z1 + z2 + z3;
    float sq = z0*z0 + z1*z1 + z2*z2 + z3*z3;
    s += __shfl_xor(s, 1);  sq += __shfl_xor(sq, 1);
    s += __shfl_xor(s, 2);  sq += __shfl_xor(sq, 2);
    s += __shfl_xor(s, 4);  sq += __shfl_xor(sq, 4);
    s += __shfl_xor(s, 8);  sq += __shfl_xor(sq, 8);
    s += __shfl_xor(s, 16); sq += __shfl_xor(sq, 16);
    float mu = s * (1.0f / 128.0f);
    float var = sq * (1.0f / 128.0f) - mu * mu;
    float inv = rsqrtf(var + 1e-5f);
    if (row < N){
      float4 o;
      o.x = (z0 - mu) * inv * gg.x + b2t.x;
      o.y = (z1 - mu) * inv * gg.y + b2t.y;
      o.z = (z2 - mu) * inv * gg.z + b2t.z;
      o.w = (z3 - mu) * inv * gg.w + b2t.w;
      *(float4*)(out + (size_t)row * 128 + tx * 4) = o;
    }
  }
}

extern "C" void kernel_launch(void* const* d_in, const int* in_sizes, int n_in,
                              void* d_out, int out_size, void* d_ws, size_t ws_size,
                              hipStream_t stream){
  const float* x      = (const float*)d_in[0];
  const int*   ei     = (const int*)d_in[1];     // integer inputs arrive as int32
  const float* w_gcn  = (const float*)d_in[2];
  const float* b_gcn  = (const float*)d_in[3];
  const float* w_q    = (const float*)d_in[4];
  const float* b_q    = (const float*)d_in[5];
  const float* w_k    = (const float*)d_in[6];
  const float* b_k    = (const float*)d_in[7];
  const float* w_v    = (const float*)d_in[8];
  const float* b_v    = (const float*)d_in[9];
  const float* w_skip = (const float*)d_in[10];
  const float* b_skip = (const float*)d_in[11];
  const float* w_beta = (const float*)d_in[12];
  const float* ln1_g  = (const float*)d_in[13];
  const float* ln1_b  = (const float*)d_in[14];
  const float* ln2_g  = (const float*)d_in[15];
  const float* ln2_b  = (const float*)d_in[16];
  const float* w1     = (const float*)d_in[17];
  const float* b1     = (const float*)d_in[18];
  const float* w2     = (const float*)d_in[19];
  const float* b2     = (const float*)d_in[20];
  const float* lw     = (const float*)d_in[21];
  const float* gw     = (const float*)d_in[22];
  int N = in_sizes[0] / 128;
  int E = in_sizes[1] / 2;
  float* outf = (float*)d_out;
  float* xn   = (float*)d_out;   // xn lives in d_out; ffn2 overwrites in place (per-row, read-before-write)

  char* ws = (char*)d_ws;
  size_t off = 0;
  auto alloc = [&](size_t bytes) -> char* {
    char* p = ws + off; off += (bytes + 255) & ~(size_t)255; return p;
  };
  u16* kvhB   = (u16*)alloc((size_t)N * 384 * 2);   // [k | v | h] bf16 per node, 768B blocks
  u16* xrB    = (u16*)alloc((size_t)N * 128 * 2);
  u16* qB     = (u16*)alloc((size_t)N * 128 * 2);
  int* csr    = (int*)alloc((size_t)E * 4);
  int* deg    = (int*)alloc((size_t)N * 4);
  int* rowptr = (int*)alloc((size_t)(N + 1) * 4);
  int* fill   = (int*)alloc((size_t)N * 4);
  float* dinv = (float*)alloc((size_t)N * 4);
  int NB = (N + 1023) >> 10;
  int* bsum   = (int*)alloc((size_t)NB * 4);
  int* boff   = (int*)alloc((size_t)NB * 4);
  float* Wcat = (float*)alloc((size_t)128 * 640 * 4);
  float* bcat = (float*)alloc((size_t)640 * 4);
  u16* hid    = (u16*)kvhB;      // alias: kvhB dead after k_edge; hid needs N*256*2 <= N*384*2

  if (off > ws_size) return;     // workspace too small: bail cleanly (absmax fail, not a crash)

  hipMemsetAsync(deg, 0, (size_t)N * 4, stream);
  hipMemsetAsync(fill, 0, (size_t)N * 4, stream);

  k_prep<<<320, 256, 0, stream>>>(w_q, b_q, w_skip, b_skip, w_k, b_k, w_v, b_v, w_gcn, Wcat, bcat);
  k_hist<<<(E + 255) / 256, 256, 0, stream>>>(ei, E, deg);
  k_scan_a<<<NB, 256, 0, stream>>>(deg, N, bsum);
  k_scan_b<<<1, 1024, 0, stream>>>(bsum, NB, boff);
  k_scan_c<<<NB, 256, 0, stream>>>(deg, N, E, boff, rowptr);
  k_dinv<<<(N + 255) / 256, 256, 0, stream>>>(deg, N, dinv);
  k_csr<<<(E + 255) / 256, 256, 0, stream>>>(ei, E, rowptr, fill, csr);

  int MB = (N + 63) / 64;
  dim3 g1(MB, 10);
  k_gemm1<<<g1, 256, 0, stream>>>(x, Wcat, bcat, qB, xrB, kvhB, N);
  k_edge<<<(N + 3) / 4, 256, 0, stream>>>(qB, xrB, kvhB, csr, rowptr, dinv, b_gcn, w_beta,
                                          ln1_g, ln1_b, lw, gw, xn, N);
  dim3 f1(MB, 4);
  k_ffn1<<<f1, 256, 0, stream>>>(xn, w1, b1, hid, N);
  k_ffn2<<<MB, 512, 0, stream>>>(hid, w2, b2, xn, ln2_g, ln2_b, outf, N);
}

// Round 4
// 477.949 us; speedup vs baseline: 1.6773x; 1.6773x over previous
//
#include <hip/hip_runtime.h>

typedef unsigned int u32;
typedef unsigned short u16;
typedef __attribute__((ext_vector_type(8))) short bf16x8;
typedef __attribute__((ext_vector_type(4))) float f32x4;

__device__ __forceinline__ float bf2f(u16 u){ return __uint_as_float(((u32)u) << 16); }
__device__ __forceinline__ u16 f2bf(float f){
  u32 x = __float_as_uint(f);
  return (u16)((x + 0x7fffu + ((x >> 16) & 1u)) >> 16);  // RNE
}

// ---------- prep: WcatT[640][128], w1T[256][128], w2T[128][256] (all bf16, [outcol][k]) + bcat ----------
__global__ void k_prep_all(const float* wq, const float* bq, const float* wsk, const float* bsk,
                           const float* wk, const float* bk, const float* wv, const float* bv,
                           const float* wg, const float* w1, const float* w2,
                           u16* WcatT, float* bcat, u16* w1T, u16* w2T){
  int idx = blockIdx.x * 256 + threadIdx.x;
  if (idx < 640 * 128){
    int col = idx >> 7, k = idx & 127;
    int blk = col >> 7, c = col & 127;
    const float* w = (blk==0)?wq:(blk==1)?wsk:(blk==2)?wk:(blk==3)?wv:wg;
    WcatT[idx] = f2bf(w[k * 128 + c]);
    if (k == 0){
      const float* b = (blk==0)?bq:(blk==1)?bsk:(blk==2)?bk:(blk==3)?bv:nullptr;
      bcat[col] = b ? b[c] : 0.0f;   // gcn bias added after aggregation
    }
  } else if (idx < 640*128 + 256*128){
    int j = idx - 640*128; int c = j >> 7, k = j & 127;
    w1T[j] = f2bf(w1[k * 256 + c]);
  } else if (idx < 640*128 + 256*128 + 128*256){
    int j = idx - (640*128 + 256*128); int c = j >> 8, k = j & 255;
    w2T[j] = f2bf(w2[k * 128 + c]);
  }
}

// ---------- x (f32) -> xB (bf16) ----------
__global__ void k_cvt(const float* __restrict__ x, u16* __restrict__ xB, int n){
  int i = (blockIdx.x * 256 + threadIdx.x) * 4;
  if (i >= n) return;
  float4 v = *(const float4*)(x + i);
  ushort4 o; o.x = f2bf(v.x); o.y = f2bf(v.y); o.z = f2bf(v.z); o.w = f2bf(v.w);
  *(ushort4*)(xB + i) = o;
}

// ---------- graph prep (edge_index is int32: src=ei[e], dst=ei[E+e]) ----------
__global__ void k_hist(const int* __restrict__ ei, int E, int* __restrict__ deg){
  int e = blockIdx.x * 256 + threadIdx.x;
  if (e >= E) return;
  atomicAdd(&deg[ei[E + e]], 1);
}
__global__ void k_scan_a(const int* __restrict__ deg, int N, int* __restrict__ bsum){
  __shared__ int sh[256];
  int b = blockIdx.x, t = threadIdx.x;
  int base = b * 1024 + t * 4, s = 0;
  #pragma unroll
  for (int j = 0; j < 4; j++){ int i = base + j; if (i < N) s += deg[i]; }
  sh[t] = s; __syncthreads();
  for (int off = 128; off > 0; off >>= 1){ if (t < off) sh[t] += sh[t + off]; __syncthreads(); }
  if (t == 0) bsum[b] = sh[0];
}
__global__ void k_scan_b(const int* __restrict__ bsum, int NB, int* __restrict__ boff){
  __shared__ int sh[1024];
  int t = threadIdx.x;
  int self = (t < NB) ? bsum[t] : 0;
  sh[t] = self; __syncthreads();
  for (int off = 1; off < 1024; off <<= 1){
    int v = sh[t]; int add = (t >= off) ? sh[t - off] : 0;
    __syncthreads(); sh[t] = v + add; __syncthreads();
  }
  if (t < NB) boff[t] = sh[t] - self;
}
__global__ void k_scan_c(const int* __restrict__ deg, int N, int E,
                         const int* __restrict__ boff, int* __restrict__ rowptr){
  __shared__ int sh[256];
  int b = blockIdx.x, t = threadIdx.x;
  int base = b * 1024 + t * 4;
  int d[4]; int ts = 0;
  #pragma unroll
  for (int j = 0; j < 4; j++){ int i = base + j; d[j] = (i < N) ? deg[i] : 0; ts += d[j]; }
  sh[t] = ts; __syncthreads();
  for (int off = 1; off < 256; off <<= 1){
    int v = sh[t]; int add = (t >= off) ? sh[t - off] : 0;
    __syncthreads(); sh[t] = v + add; __syncthreads();
  }
  int excl = sh[t] - ts + boff[b];
  #pragma unroll
  for (int j = 0; j < 4; j++){ int i = base + j; if (i < N) rowptr[i] = excl; excl += d[j]; }
  if (b == 0 && t == 0) rowptr[N] = E;
}
__global__ void k_dinv(const int* __restrict__ deg, int N, float* __restrict__ dinv){
  int i = blockIdx.x * 256 + threadIdx.x;
  if (i < N) dinv[i] = deg[i] > 0 ? rsqrtf((float)deg[i]) : 0.0f;
}
__global__ void k_csr(const int* __restrict__ ei, int E,
                      const int* __restrict__ rowptr, int* __restrict__ fill, int* __restrict__ csr){
  int e = blockIdx.x * 256 + threadIdx.x;
  if (e >= E) return;
  int d = ei[E + e];
  int pos = rowptr[d] + atomicAdd(&fill[d], 1);
  csr[pos] = ei[e];
}

// ---------- MFMA tile helpers: 128 rows x 128 halves, XOR-swizzled LDS ----------
__device__ __forceinline__ void stageTile(const u16* __restrict__ g, int ldg, int row0, int rclamp,
                                          int kofs, u16* lds){
  int t = threadIdx.x;
  #pragma unroll
  for (int p = 0; p < 8; p++){
    int chunk = p * 256 + t;          // 2048 chunks of 8 halves
    int r = chunk >> 4;
    int cs = (chunk & 15) << 3;
    int rg = row0 + r; if (rg >= rclamp) rg = rclamp - 1;
    bf16x8 v = *(const bf16x8*)(g + (size_t)rg * ldg + kofs + cs);
    *(bf16x8*)(lds + r * 128 + (cs ^ ((r & 7) << 3))) = v;
  }
}
__device__ __forceinline__ bf16x8 ldFrag(const u16* lds, int r, int k0){
  return *(const bf16x8*)(lds + r * 128 + (k0 ^ ((r & 7) << 3)));
}

// ---------- GEMM1 (MFMA): [q | xr | k,v,h] bf16 = xB @ WcatT^T + bcat ----------
__global__ __launch_bounds__(256) void k_gemm1(const u16* __restrict__ xB, const u16* __restrict__ WcatT,
    const float* __restrict__ bcat, u16* __restrict__ qB, u16* __restrict__ xrB,
    u16* __restrict__ kvhB, int N){
  __shared__ u16 As[128 * 128];
  __shared__ u16 Bs[128 * 128];
  int row0 = blockIdx.x * 128, cb = blockIdx.y;
  stageTile(xB, 128, row0, N, 0, As);
  stageTile(WcatT, 128, cb * 128, 1 << 30, 0, Bs);
  __syncthreads();
  int t = threadIdx.x, l = t & 63, w = t >> 6;
  int wm = w >> 1, wn = w & 1;
  int c16 = l & 15, g = l >> 4;
  f32x4 acc[4][4];
  #pragma unroll
  for (int mi = 0; mi < 4; mi++)
    #pragma unroll
    for (int ni = 0; ni < 4; ni++) acc[mi][ni] = (f32x4){0.f, 0.f, 0.f, 0.f};
  #pragma unroll
  for (int kk = 0; kk < 4; kk++){
    int k0 = kk * 32 + g * 8;
    bf16x8 af[4], bfr[4];
    #pragma unroll
    for (int mi = 0; mi < 4; mi++) af[mi] = ldFrag(As, wm * 64 + mi * 16 + c16, k0);
    #pragma unroll
    for (int ni = 0; ni < 4; ni++) bfr[ni] = ldFrag(Bs, wn * 64 + ni * 16 + c16, k0);
    #pragma unroll
    for (int mi = 0; mi < 4; mi++)
      #pragma unroll
      for (int ni = 0; ni < 4; ni++)
        acc[mi][ni] = __builtin_amdgcn_mfma_f32_16x16x32_bf16(af[mi], bfr[ni], acc[mi][ni], 0, 0, 0);
  }
  u16* dst; int ld, cofs;
  if (cb == 0){ dst = qB;  ld = 128; cofs = 0; }
  else if (cb == 1){ dst = xrB; ld = 128; cofs = 0; }
  else { dst = kvhB; ld = 384; cofs = (cb - 2) * 128; }
  float bias[4];
  #pragma unroll
  for (int ni = 0; ni < 4; ni++) bias[ni] = bcat[cb * 128 + wn * 64 + ni * 16 + c16];
  #pragma unroll
  for (int mi = 0; mi < 4; mi++){
    #pragma unroll
    for (int r = 0; r < 4; r++){
      int row = row0 + wm * 64 + mi * 16 + g * 4 + r;
      if (row < N){
        #pragma unroll
        for (int ni = 0; ni < 4; ni++)
          dst[(size_t)row * ld + cofs + wn * 64 + ni * 16 + c16] = f2bf(acc[mi][ni][r] + bias[ni]);
      }
    }
  }
}

// ---------- edge pass: per-dst attention + GCN aggregate + beta gate + LN1, one wave per node ----------
__global__ __launch_bounds__(256) void k_edge(const u16* __restrict__ qB, const u16* __restrict__ xrB,
    const u16* __restrict__ kvhB,
    const int* __restrict__ csr, const int* __restrict__ rowptr, const float* __restrict__ dinv,
    const float* __restrict__ bgcn, const float* __restrict__ wbeta,
    const float* __restrict__ lng, const float* __restrict__ lnb,
    const float* __restrict__ lwp, const float* __restrict__ gwp,
    float* __restrict__ xn, u16* __restrict__ xnB, int N){
  int lane = threadIdx.x & 63;
  int n = blockIdx.x * 4 + (threadIdx.x >> 6);
  if (n >= N) return;
  int ro = rowptr[n], re = rowptr[n + 1];
  u32 qu = *(const u32*)(qB + (size_t)n * 128 + 2 * lane);
  float q0 = bf2f((u16)(qu & 0xffff)), q1 = bf2f((u16)(qu >> 16));
  float av0 = 0, av1 = 0, ah0 = 0, ah1 = 0, den = 0;
  int sNext = (ro < re) ? csr[ro] : 0;
  for (int e = ro; e < re; e++){
    int s = sNext;
    if (e + 1 < re) sNext = csr[e + 1];
    const u16* fb = kvhB + (size_t)s * 384;
    u32 ku = *(const u32*)(fb + 2 * lane);
    u32 vu = *(const u32*)(fb + 128 + 2 * lane);
    u32 hu = *(const u32*)(fb + 256 + 2 * lane);
    float dv = dinv[s];
    float k0 = bf2f((u16)(ku & 0xffff)), k1 = bf2f((u16)(ku >> 16));
    float part = q0 * k0 + q1 * k1;                 // head = lane/16
    part += __shfl_xor(part, 1);
    part += __shfl_xor(part, 2);
    part += __shfl_xor(part, 4);
    part += __shfl_xor(part, 8);
    float p = __expf(part * 0.17677669529663687f);  // 1/sqrt(32)
    float v0 = bf2f((u16)(vu & 0xffff)), v1 = bf2f((u16)(vu >> 16));
    float h0 = bf2f((u16)(hu & 0xffff)), h1 = bf2f((u16)(hu >> 16));
    av0 += p * v0; av1 += p * v1;
    ah0 += dv * h0; ah1 += dv * h1;
    den += p;
  }
  float at0 = den > 0 ? av0 / den : 0.0f;
  float at1 = den > 0 ? av1 / den : 0.0f;
  u32 xru = *(const u32*)(xrB + (size_t)n * 128 + 2 * lane);
  float xr0 = bf2f((u16)(xru & 0xffff)), xr1 = bf2f((u16)(xru >> 16));
  float z = at0 * wbeta[2*lane] + at1 * wbeta[2*lane+1]
          + xr0 * wbeta[128 + 2*lane] + xr1 * wbeta[129 + 2*lane]
          + (at0 - xr0) * wbeta[256 + 2*lane] + (at1 - xr1) * wbeta[257 + 2*lane];
  z += __shfl_xor(z, 1); z += __shfl_xor(z, 2); z += __shfl_xor(z, 4);
  z += __shfl_xor(z, 8); z += __shfl_xor(z, 16); z += __shfl_xor(z, 32);
  float beta = 1.0f / (1.0f + __expf(-z));
  float dn = dinv[n];
  float l0 = dn * ah0 + bgcn[2*lane], l1 = dn * ah1 + bgcn[2*lane+1];
  float g0 = beta * xr0 + (1.0f - beta) * at0;
  float g1v = beta * xr1 + (1.0f - beta) * at1;
  float lw = lwp[0], gw = gwp[0];
  float t0 = 2.0f * (lw * l0 + gw * g0);
  float t1 = 2.0f * (lw * l1 + gw * g1v);
  float s = t0 + t1, sq = t0 * t0 + t1 * t1;
  s += __shfl_xor(s, 1);  sq += __shfl_xor(sq, 1);
  s += __shfl_xor(s, 2);  sq += __shfl_xor(sq, 2);
  s += __shfl_xor(s, 4);  sq += __shfl_xor(sq, 4);
  s += __shfl_xor(s, 8);  sq += __shfl_xor(sq, 8);
  s += __shfl_xor(s, 16); sq += __shfl_xor(sq, 16);
  s += __shfl_xor(s, 32); sq += __shfl_xor(sq, 32);
  float mu = s * (1.0f / 128.0f);
  float var = sq * (1.0f / 128.0f) - mu * mu;
  float inv = rsqrtf(var + 1e-5f);
  float o0 = (t0 - mu) * inv * lng[2*lane] + lnb[2*lane];
  float o1 = (t1 - mu) * inv * lng[2*lane+1] + lnb[2*lane+1];
  *(float2*)(xn + (size_t)n * 128 + 2 * lane) = make_float2(o0, o1);
  u32 pk = (u32)f2bf(o0) | ((u32)f2bf(o1) << 16);
  *(u32*)(xnB + (size_t)n * 128 + 2 * lane) = pk;
}

// ---------- FFN1 (MFMA): hid(bf16) = relu(xnB @ w1 + b1) ----------
__global__ __launch_bounds__(256) void k_ffn1(const u16* __restrict__ xnB, const u16* __restrict__ w1T,
    const float* __restrict__ b1, u16* __restrict__ hid, int N){
  __shared__ u16 As[128 * 128];
  __shared__ u16 Bs[128 * 128];
  int row0 = blockIdx.x * 128, cb = blockIdx.y;
  stageTile(xnB, 128, row0, N, 0, As);
  stageTile(w1T, 128, cb * 128, 1 << 30, 0, Bs);
  __syncthreads();
  int t = threadIdx.x, l = t & 63, w = t >> 6;
  int wm = w >> 1, wn = w & 1;
  int c16 = l & 15, g = l >> 4;
  f32x4 acc[4][4];
  #pragma unroll
  for (int mi = 0; mi < 4; mi++)
    #pragma unroll
    for (int ni = 0; ni < 4; ni++) acc[mi][ni] = (f32x4){0.f, 0.f, 0.f, 0.f};
  #pragma unroll
  for (int kk = 0; kk < 4; kk++){
    int k0 = kk * 32 + g * 8;
    bf16x8 af[4], bfr[4];
    #pragma unroll
    for (int mi = 0; mi < 4; mi++) af[mi] = ldFrag(As, wm * 64 + mi * 16 + c16, k0);
    #pragma unroll
    for (int ni = 0; ni < 4; ni++) bfr[ni] = ldFrag(Bs, wn * 64 + ni * 16 + c16, k0);
    #pragma unroll
    for (int mi = 0; mi < 4; mi++)
      #pragma unroll
      for (int ni = 0; ni < 4; ni++)
        acc[mi][ni] = __builtin_amdgcn_mfma_f32_16x16x32_bf16(af[mi], bfr[ni], acc[mi][ni], 0, 0, 0);
  }
  float bias[4];
  #pragma unroll
  for (int ni = 0; ni < 4; ni++) bias[ni] = b1[cb * 128 + wn * 64 + ni * 16 + c16];
  #pragma unroll
  for (int mi = 0; mi < 4; mi++){
    #pragma unroll
    for (int r = 0; r < 4; r++){
      int row = row0 + wm * 64 + mi * 16 + g * 4 + r;
      if (row < N){
        #pragma unroll
        for (int ni = 0; ni < 4; ni++)
          hid[(size_t)row * 256 + cb * 128 + wn * 64 + ni * 16 + c16] =
              f2bf(fmaxf(acc[mi][ni][r] + bias[ni], 0.0f));
      }
    }
  }
}

// ---------- FFN2 (MFMA) + residual + LN2 -> out (f32, in place over xn) ----------
__global__ __launch_bounds__(256) void k_ffn2(const u16* __restrict__ hid, const u16* __restrict__ w2T,
    const float* __restrict__ b2, const float* __restrict__ xnf,
    const float* __restrict__ g2, const float* __restrict__ bt2,
    float* __restrict__ out, int N){
  __shared__ u16 As[128 * 128];
  __shared__ u16 Bs[128 * 128];
  int row0 = blockIdx.x * 128;
  int t = threadIdx.x, l = t & 63, w = t >> 6;    // wave grid 4x1: rows w*32..+31, all 128 cols
  int c16 = l & 15, g = l >> 4;
  f32x4 acc[2][8];
  #pragma unroll
  for (int mi = 0; mi < 2; mi++)
    #pragma unroll
    for (int ni = 0; ni < 8; ni++) acc[mi][ni] = (f32x4){0.f, 0.f, 0.f, 0.f};
  for (int kc = 0; kc < 2; kc++){
    if (kc) __syncthreads();
    stageTile(hid, 256, row0, N, kc * 128, As);
    stageTile(w2T, 256, 0, 1 << 30, kc * 128, Bs);
    __syncthreads();
    #pragma unroll
    for (int kk = 0; kk < 4; kk++){
      int k0 = kk * 32 + g * 8;
      bf16x8 af[2], bfr[8];
      #pragma unroll
      for (int mi = 0; mi < 2; mi++) af[mi] = ldFrag(As, w * 32 + mi * 16 + c16, k0);
      #pragma unroll
      for (int ni = 0; ni < 8; ni++) bfr[ni] = ldFrag(Bs, ni * 16 + c16, k0);
      #pragma unroll
      for (int mi = 0; mi < 2; mi++)
        #pragma unroll
        for (int ni = 0; ni < 8; ni++)
          acc[mi][ni] = __builtin_amdgcn_mfma_f32_16x16x32_bf16(af[mi], bfr[ni], acc[mi][ni], 0, 0, 0);
    }
  }
  float b2c[8], g2c[8], btc[8];
  #pragma unroll
  for (int ni = 0; ni < 8; ni++){
    int col = ni * 16 + c16;
    b2c[ni] = b2[col]; g2c[ni] = g2[col]; btc[ni] = bt2[col];
  }
  #pragma unroll
  for (int mi = 0; mi < 2; mi++){
    #pragma unroll
    for (int r = 0; r < 4; r++){
      int row = row0 + w * 32 + mi * 16 + g * 4 + r;
      int rc = row < N ? row : N - 1;
      float z[8]; float s = 0.f, sq = 0.f;
      #pragma unroll
      for (int ni = 0; ni < 8; ni++){
        z[ni] = acc[mi][ni][r] + b2c[ni] + xnf[(size_t)rc * 128 + ni * 16 + c16];
        s += z[ni]; sq += z[ni] * z[ni];
      }
      s += __shfl_xor(s, 1); sq += __shfl_xor(sq, 1);
      s += __shfl_xor(s, 2); sq += __shfl_xor(sq, 2);
      s += __shfl_xor(s, 4); sq += __shfl_xor(sq, 4);
      s += __shfl_xor(s, 8); sq += __shfl_xor(sq, 8);
      float mu = s * (1.0f / 128.0f);
      float var = sq * (1.0f / 128.0f) - mu * mu;
      float inv = rsqrtf(var + 1e-5f);
      if (row < N){
        #pragma unroll
        for (int ni = 0; ni < 8; ni++)
          out[(size_t)row * 128 + ni * 16 + c16] = (z[ni] - mu) * inv * g2c[ni] + btc[ni];
      }
    }
  }
}

extern "C" void kernel_launch(void* const* d_in, const int* in_sizes, int n_in,
                              void* d_out, int out_size, void* d_ws, size_t ws_size,
                              hipStream_t stream){
  const float* x      = (const float*)d_in[0];
  const int*   ei     = (const int*)d_in[1];
  const float* w_gcn  = (const float*)d_in[2];
  const float* b_gcn  = (const float*)d_in[3];
  const float* w_q    = (const float*)d_in[4];
  const float* b_q    = (const float*)d_in[5];
  const float* w_k    = (const float*)d_in[6];
  const float* b_k    = (const float*)d_in[7];
  const float* w_v    = (const float*)d_in[8];
  const float* b_v    = (const float*)d_in[9];
  const float* w_skip = (const float*)d_in[10];
  const float* b_skip = (const float*)d_in[11];
  const float* w_beta = (const float*)d_in[12];
  const float* ln1_g  = (const float*)d_in[13];
  const float* ln1_b  = (const float*)d_in[14];
  const float* ln2_g  = (const float*)d_in[15];
  const float* ln2_b  = (const float*)d_in[16];
  const float* w1     = (const float*)d_in[17];
  const float* b1     = (const float*)d_in[18];
  const float* w2     = (const float*)d_in[19];
  const float* b2     = (const float*)d_in[20];
  const float* lw     = (const float*)d_in[21];
  const float* gw     = (const float*)d_in[22];
  int N = in_sizes[0] / 128;
  int E = in_sizes[1] / 2;
  float* outf = (float*)d_out;
  float* xn   = (float*)d_out;   // xn lives in d_out; ffn2 reads-then-overwrites per element

  char* ws = (char*)d_ws;
  size_t off = 0;
  auto alloc = [&](size_t bytes) -> char* {
    char* p = ws + off; off += (bytes + 255) & ~(size_t)255; return p;
  };
  u16* kvhB   = (u16*)alloc((size_t)N * 384 * 2);   // [k | v | h] bf16; aliased by hid after edge
  u16* xrB    = (u16*)alloc((size_t)N * 128 * 2);
  u16* qB     = (u16*)alloc((size_t)N * 128 * 2);
  u16* xB     = (u16*)alloc((size_t)N * 128 * 2);   // x bf16; aliased by xnB after gemm1
  int* csr    = (int*)alloc((size_t)E * 4);
  int* deg    = (int*)alloc((size_t)N * 4);
  int* rowptr = (int*)alloc((size_t)(N + 1) * 4);
  int* fill   = (int*)alloc((size_t)N * 4);
  float* dinv = (float*)alloc((size_t)N * 4);
  int NB = (N + 1023) >> 10;
  int* bsum   = (int*)alloc((size_t)NB * 4);
  int* boff   = (int*)alloc((size_t)NB * 4);
  u16* WcatT  = (u16*)alloc((size_t)640 * 128 * 2);
  float* bcat = (float*)alloc((size_t)640 * 4);
  u16* w1T    = (u16*)alloc((size_t)256 * 128 * 2);
  u16* w2T    = (u16*)alloc((size_t)128 * 256 * 2);
  u16* hid    = kvhB;            // alias: kvhB dead after k_edge (N*256*2 <= N*384*2)
  u16* xnB    = xB;              // alias: xB dead after k_gemm1

  if (off > ws_size) return;     // bail cleanly if workspace too small

  hipMemsetAsync(deg, 0, (size_t)N * 4, stream);
  hipMemsetAsync(fill, 0, (size_t)N * 4, stream);

  k_prep_all<<<576, 256, 0, stream>>>(w_q, b_q, w_skip, b_skip, w_k, b_k, w_v, b_v, w_gcn,
                                      w1, w2, WcatT, bcat, w1T, w2T);
  k_cvt<<<(N * 128 / 4 + 255) / 256, 256, 0, stream>>>(x, xB, N * 128);
  k_hist<<<(E + 255) / 256, 256, 0, stream>>>(ei, E, deg);
  k_scan_a<<<NB, 256, 0, stream>>>(deg, N, bsum);
  k_scan_b<<<1, 1024, 0, stream>>>(bsum, NB, boff);
  k_scan_c<<<NB, 256, 0, stream>>>(deg, N, E, boff, rowptr);
  k_dinv<<<(N + 255) / 256, 256, 0, stream>>>(deg, N, dinv);
  k_csr<<<(E + 255) / 256, 256, 0, stream>>>(ei, E, rowptr, fill, csr);

  int MB = (N + 127) / 128;
  dim3 g1(MB, 5);
  k_gemm1<<<g1, 256, 0, stream>>>(xB, WcatT, bcat, qB, xrB, kvhB, N);
  k_edge<<<(N + 3) / 4, 256, 0, stream>>>(qB, xrB, kvhB, csr, rowptr, dinv, b_gcn, w_beta,
                                          ln1_g, ln1_b, lw, gw, xn, xnB, N);
  dim3 f1(MB, 2);
  k_ffn1<<<f1, 256, 0, stream>>>(xnB, w1T, b1, hid, N);
  k_ffn2<<<MB, 256, 0, stream>>>(hid, w2T, b2, xn, ln2_g, ln2_b, outf, N);
}